// Round 19
// baseline (200.831 us; speedup 1.0000x reference)
//
#include <hip/hip_runtime.h>

#define K_CODES 1024
#define DIM 128
#define HW 1024
#define NTOT 65536
#define DECAY 0.99f
#define OMD 0.01f
#define EPS 1e-5f
#define CCOEF 0.25f
#define MARGIN 1e-4f
#define FLCAP 24576

// d_out offsets (floats)
#define OFF_Q    0
#define OFF_IDX  8388608
#define OFF_LOSS (8388608 + 65536)
#define OFF_EMB  (OFF_LOSS + 1)
#define OFF_ECS  (OFF_EMB + 131072)
#define OFF_EMAW (OFF_ECS + 1024)

// workspace layout (word offsets); hist..cnt contiguous zero span (25604 wds)
#define W_NORM2 0
#define W_RCP   1024
#define W_HIST  2048
#define W_LOSS  3072
#define W_FLCNT 3073
#define W_RDONE 3074                   // last-block counter (krescore)
#define W_QDONE 3075                   // last-block counter (ktail/quant)
#define W_CNT2  3076
#define W_FL    (3076 + 24576)
#define W_M1F   (27652 + 24576)
#define W_CAND  (52228 + 24576)
#define W_EH    (76804 + 196608)       // 273412 (PRE-SWIZZLED layout)
#define W_EL    (273412 + 65536)       // 338948
#define W_NXIDX (338948 + 65536)       // 404484
#define W_FLAT  (404484 + 65536)       // 470020
#define W_NEED  (470020 + 8388608)

typedef __attribute__((ext_vector_type(8))) short short8v;
typedef __attribute__((ext_vector_type(4))) float f32x4;

__device__ __forceinline__ unsigned short f2bf(float f) {
    unsigned u = __float_as_uint(f);
    u += 0x7fffu + ((u >> 16) & 1u);
    return (unsigned short)(u >> 16);
}
__device__ __forceinline__ float bf2f(unsigned short h) {
    return __uint_as_float(((unsigned)h) << 16);
}

__global__ __launch_bounds__(256) void kzero(float* __restrict__ p, int n) {
    int i = blockIdx.x * 256 + threadIdx.x;
    if (i < n) p[i] = 0.f;
}

// numpy pairwise_sum replica (per-thread form) — verified.
__device__ __forceinline__ float np_pairwise_sumsq_128(const float* p, size_t stride) {
    float r[8][4];
    #pragma unroll
    for (int j = 0; j < 8; ++j)
        #pragma unroll
        for (int L = 0; L < 4; ++L) {
            float x = p[(size_t)(j * 4 + L) * stride];
            r[j][L] = __fmul_rn(x, x);
        }
    #pragma unroll
    for (int c = 1; c < 4; ++c)
        #pragma unroll
        for (int j = 0; j < 8; ++j)
            #pragma unroll
            for (int L = 0; L < 4; ++L) {
                float x = p[(size_t)(c * 32 + j * 4 + L) * stride];
                r[j][L] = __fadd_rn(r[j][L], __fmul_rn(x, x));
            }
    float V[4];
    #pragma unroll
    for (int L = 0; L < 4; ++L) {
        float a = __fadd_rn(r[0][L], r[1][L]);
        float b = __fadd_rn(r[2][L], r[3][L]);
        float c2 = __fadd_rn(r[4][L], r[5][L]);
        float d2 = __fadd_rn(r[6][L], r[7][L]);
        V[L] = __fadd_rn(__fadd_rn(a, b), __fadd_rn(c2, d2));
    }
    return __fadd_rn(__fadd_rn(V[0], V[1]), __fadd_rn(V[2], V[3]));
}

// FUSED preprocessing (r18-verified): blocks 0..511 = transpose+nx+flat_c;
// blocks 512..639 = zero accumulators + norm2 + pre-swizzled bf16 split.
__global__ __launch_bounds__(256) void kpre(
    const float* __restrict__ ze, float* __restrict__ nx,
    float* __restrict__ flat_c, const float* __restrict__ embed,
    float* __restrict__ norm2, unsigned short* __restrict__ ehs_g,
    unsigned short* __restrict__ els_g, float* __restrict__ zero_p, int zero_n)
{
    __shared__ float t[128][133];
    const int tid = threadIdx.x;
    const int bid = blockIdx.x;
    if (bid < 512) {
        const int n0 = bid * 128;
        const int b = n0 >> 10, hw0 = n0 & (HW - 1);
        const float* zb = ze + (size_t)b * (DIM * HW) + hw0;
        #pragma unroll
        for (int i = 0; i < 64; ++i) {
            int d = i * 2 + (tid >> 7);
            int hw = tid & 127;
            t[hw][d] = zb[(size_t)d * HW + hw];
        }
        __syncthreads();
        if (tid < 128) nx[n0 + tid] = np_pairwise_sumsq_128(&t[tid][0], 1);
        if (flat_c) {
            #pragma unroll
            for (int i = 0; i < 16; ++i) {
                int lin = i * 256 + tid;
                int r  = lin >> 5;
                int c4 = lin & 31;
                float4 v = *(const float4*)&t[r][c4 * 4];
                *(float4*)&flat_c[(size_t)(n0 + r) * DIM + c4 * 4] = v;
            }
        }
    } else {
        const int pid = bid - 512;
        int zi = pid * 256 + tid;
        if (zi < zero_n) zero_p[zi] = 0.f;
        {
            const int g32 = tid >> 5, l32 = tid & 31;
            const int k = pid * 8 + g32;
            const float* row = embed + (size_t)k * DIM;
            float x = row[l32];
            float r = __fmul_rn(x, x);
            #pragma unroll
            for (int c = 1; c < 4; ++c) {
                float y = row[c * 32 + l32];
                r = __fadd_rn(r, __fmul_rn(y, y));
            }
            float s1 = __fadd_rn(r, __shfl_xor(r, 4, 64));
            float s2 = __fadd_rn(s1, __shfl_xor(s1, 8, 64));
            float s3 = __fadd_rn(s2, __shfl_xor(s2, 16, 64));
            float h1 = __fadd_rn(s3, __shfl_xor(s3, 1, 64));
            float h2 = __fadd_rn(h1, __shfl_xor(h1, 2, 64));
            if (l32 == 0) norm2[k] = h2;
        }
        if (ehs_g) {
            int hu = pid * 256 + tid;
            int U = hu >> 1, half = hu & 1;
            int code = U >> 4;
            int g = (U & 15) ^ (code & 15);
            const float* src = embed + (size_t)code * DIM + g * 8 + half * 4;
            float4 f = *(const float4*)src;
            unsigned short a = f2bf(f.x), b = f2bf(f.y), c = f2bf(f.z), d = f2bf(f.w);
            ushort4 hi; hi.x = a; hi.y = b; hi.z = c; hi.w = d;
            ushort4 lo;
            lo.x = f2bf(f.x - bf2f(a)); lo.y = f2bf(f.y - bf2f(b));
            lo.z = f2bf(f.z - bf2f(c)); lo.w = f2bf(f.w - bf2f(d));
            *(ushort4*)(ehs_g + (size_t)U * 8 + half * 4) = hi;
            *(ushort4*)(els_g + (size_t)U * 8 + half * 4) = lo;
        }
    }
}

// bf16x3 MFMA single-pass argmin (r17 structure). Min-track split into two
// independent chains (A = codes it*32+lg*4+r, B = +16), merged at the end
// with the exact min2-union formula -> (m1,c1,m2) bit-identical to the
// sequential fold (streaming min1/min2 = exact order statistics).
__global__ __launch_bounds__(256, 4) void kapprox(
    const float* __restrict__ flat_c, const unsigned short* __restrict__ eh_g,
    const unsigned short* __restrict__ el_g, const float* __restrict__ norm2,
    int* __restrict__ idx_ws, float* __restrict__ idx_out,
    unsigned* __restrict__ hist, unsigned* __restrict__ flcnt,
    unsigned* __restrict__ fl_list, float* __restrict__ m1f)
{
    __shared__ __align__(16) unsigned short ehs[2][32 * 128];
    __shared__ __align__(16) unsigned short els[2][32 * 128];
    __shared__ float nes[1024];

    const int tid = threadIdx.x;
    const int l = tid & 63;
    const int w = tid >> 6;
    const int lg = l >> 4;
    const int lm = l & 15;
    const int n0 = blockIdx.x * 64;

    for (int i = tid; i < 1024; i += 256) nes[i] = norm2[i];

    short8v xh[4], xl[4];
    {
        const float* xr = flat_c + (size_t)(n0 + w * 16 + lm) * DIM;
        #pragma unroll
        for (int ks = 0; ks < 4; ++ks) {
            int kb = ks * 32 + lg * 8;
            float f0[8];
            *(float4*)&f0[0] = *(const float4*)(xr + kb);
            *(float4*)&f0[4] = *(const float4*)(xr + kb + 4);
            #pragma unroll
            for (int e = 0; e < 8; ++e) {
                unsigned short h0 = f2bf(f0[e]);
                xh[ks][e] = (short)h0;
                xl[ks][e] = (short)f2bf(f0[e] - bf2f(h0));
            }
        }
    }

    int roff[4];
    #pragma unroll
    for (int ks = 0; ks < 4; ++ks)
        roff[ks] = lm * 128 + (((ks * 4 + lg) ^ lm) * 8);

    const int su0 = tid * 8;
    const int su1 = 2048 + tid * 8;

    uint4 peh0 = *(const uint4*)(eh_g + su0);
    uint4 peh1 = *(const uint4*)(eh_g + su1);
    uint4 pel0 = *(const uint4*)(el_g + su0);
    uint4 pel1 = *(const uint4*)(el_g + su1);
    *(uint4*)&ehs[0][su0] = peh0;
    *(uint4*)&ehs[0][su1] = peh1;
    *(uint4*)&els[0][su0] = pel0;
    *(uint4*)&els[0][su1] = pel1;
    __syncthreads();

    float m1a = 3.4e38f, m2a = 3.4e38f, m1b = 3.4e38f, m2b = 3.4e38f;
    int c1a = 0, c1b = 0;

    for (int it = 0; it < 32; ++it) {
        const int buf = it & 1;
        const int nt = it + 1;
        if (nt < 32) {
            const size_t nb = (size_t)nt * 4096;
            peh0 = *(const uint4*)(eh_g + nb + su0);
            peh1 = *(const uint4*)(eh_g + nb + su1);
            pel0 = *(const uint4*)(el_g + nb + su0);
            pel1 = *(const uint4*)(el_g + nb + su1);
        }
        f32x4 a00 = {0.f,0.f,0.f,0.f}, a01 = {0.f,0.f,0.f,0.f};
        const unsigned short* be = &ehs[buf][0];
        const unsigned short* bl = &els[buf][0];
        #pragma unroll
        for (int ks = 0; ks < 4; ++ks) {
            short8v eA = *(const short8v*)(be + roff[ks]);
            short8v lA = *(const short8v*)(bl + roff[ks]);
            short8v eB = *(const short8v*)(be + 2048 + roff[ks]);
            short8v lB = *(const short8v*)(bl + 2048 + roff[ks]);
            a00 = __builtin_amdgcn_mfma_f32_16x16x32_bf16(eA, xh[ks], a00, 0, 0, 0);
            a00 = __builtin_amdgcn_mfma_f32_16x16x32_bf16(lA, xh[ks], a00, 0, 0, 0);
            a00 = __builtin_amdgcn_mfma_f32_16x16x32_bf16(eA, xl[ks], a00, 0, 0, 0);
            a01 = __builtin_amdgcn_mfma_f32_16x16x32_bf16(eB, xh[ks], a01, 0, 0, 0);
            a01 = __builtin_amdgcn_mfma_f32_16x16x32_bf16(lB, xh[ks], a01, 0, 0, 0);
            a01 = __builtin_amdgcn_mfma_f32_16x16x32_bf16(eB, xl[ks], a01, 0, 0, 0);
        }
        #pragma unroll
        for (int r = 0; r < 4; ++r) {
            int code0 = it * 32 + lg * 4 + r;
            int code1 = code0 + 16;
            float s0 = nes[code0] - 2.f * a00[r];
            float s1 = nes[code1] - 2.f * a01[r];
            m2a = fminf(m2a, fmaxf(m1a, s0));
            if (s0 < m1a) { m1a = s0; c1a = code0; }
            m2b = fminf(m2b, fmaxf(m1b, s1));
            if (s1 < m1b) { m1b = s1; c1b = code1; }
        }
        if (nt < 32) {
            *(uint4*)&ehs[buf ^ 1][su0] = peh0;
            *(uint4*)&ehs[buf ^ 1][su1] = peh1;
            *(uint4*)&els[buf ^ 1][su0] = pel0;
            *(uint4*)&els[buf ^ 1][su1] = pel1;
        }
        __syncthreads();
    }

    // merge the two chains (exact min2-union; lowest-code tie-break)
    float m1 = m1a, m2 = fminf(fminf(m2a, m2b), fmaxf(m1a, m1b));
    int c1 = c1a;
    if (m1b < m1a || (m1b == m1a && c1b < c1a)) { m1 = m1b; c1 = c1b; }

    #pragma unroll
    for (int mk = 16; mk <= 32; mk <<= 1) {
        float om1 = __shfl_xor(m1, mk, 64);
        int   oc1 = __shfl_xor(c1, mk, 64);
        float om2 = __shfl_xor(m2, mk, 64);
        m2 = fminf(fminf(m2, om2), fmaxf(m1, om1));
        if (om1 < m1 || (om1 == m1 && oc1 < c1)) { m1 = om1; c1 = oc1; }
    }
    if (lg == 0) {
        int n = n0 + w * 16 + lm;
        if (m2 - m1 > MARGIN) {
            idx_ws[n] = c1;
            idx_out[n] = (float)c1;
            atomicAdd(&hist[c1], 1u);
        } else {
            unsigned p = atomicAdd(flcnt, 1u);
            if (p < FLCAP) { fl_list[p] = (unsigned)n; m1f[p] = m1; }
            else {
                idx_ws[n] = c1; idx_out[n] = (float)c1;
                atomicAdd(&hist[c1], 1u);
            }
        }
    }
}

// candidate collection, WIDE (r17-verified, byte-identical).
__global__ __launch_bounds__(256, 2) void kapprox2(
    const float* __restrict__ flat_c, const unsigned short* __restrict__ eh_g,
    const unsigned short* __restrict__ el_g, const float* __restrict__ norm2,
    const float* __restrict__ m1f, const unsigned* __restrict__ flcnt,
    const unsigned* __restrict__ fl_list, unsigned* __restrict__ cnt_g,
    unsigned* __restrict__ cand_g)
{
    __shared__ __align__(16) unsigned short ehs[2][32 * 128];
    __shared__ __align__(16) unsigned short els[2][32 * 128];
    __shared__ float nes[1024];
    __shared__ unsigned ccnt[128];
    __shared__ unsigned ccode[128][8];
    __shared__ int rid[128];
    __shared__ float thrs[128];

    const int tid = threadIdx.x;
    const int l = tid & 63;
    const int w = tid >> 6;
    const int lg = l >> 4;
    const int lm = l & 15;

    for (int i = tid; i < 1024; i += 256) nes[i] = norm2[i];

    int roff[4];
    #pragma unroll
    for (int ks = 0; ks < 4; ++ks)
        roff[ks] = lm * 128 + (((ks * 4 + lg) ^ lm) * 8);

    const int su0 = tid * 8;
    const int su1 = 2048 + tid * 8;

    unsigned nflag = flcnt[0];
    if (nflag > FLCAP) nflag = FLCAP;
    const unsigned nbat = (nflag + 127u) >> 7;
    const unsigned nwork = nbat * 8u;

    for (unsigned wi = blockIdx.x; wi < nwork; wi += gridDim.x) {
        const unsigned bat = wi >> 3;
        const int cq = (int)(wi & 7u);
        __syncthreads();
        if (tid < 128) {
            unsigned p = bat * 128u + tid;
            int n = (p < nflag) ? (int)fl_list[p] : -1;
            rid[tid] = n;
            thrs[tid] = (n >= 0) ? m1f[p] + MARGIN : -3.4e38f;
            ccnt[tid] = 0;
        }
        __syncthreads();

        const int lr0 = w * 32 + lm, lr1 = lr0 + 16;
        const int nr0 = rid[lr0], nr1 = rid[lr1];
        const float thr0 = thrs[lr0], thr1 = thrs[lr1];
        short8v xh0[4], xl0[4], xh1[4], xl1[4];
        {
            const float* xr0 = flat_c + (size_t)(nr0 < 0 ? 0 : nr0) * DIM;
            const float* xr1 = flat_c + (size_t)(nr1 < 0 ? 0 : nr1) * DIM;
            #pragma unroll
            for (int ks = 0; ks < 4; ++ks) {
                int kb = ks * 32 + lg * 8;
                float f0[8], f1[8];
                *(float4*)&f0[0] = *(const float4*)(xr0 + kb);
                *(float4*)&f0[4] = *(const float4*)(xr0 + kb + 4);
                *(float4*)&f1[0] = *(const float4*)(xr1 + kb);
                *(float4*)&f1[4] = *(const float4*)(xr1 + kb + 4);
                #pragma unroll
                for (int e = 0; e < 8; ++e) {
                    unsigned short h0 = f2bf(f0[e]);
                    unsigned short h1 = f2bf(f1[e]);
                    xh0[ks][e] = (short)h0;
                    xl0[ks][e] = (short)f2bf(f0[e] - bf2f(h0));
                    xh1[ks][e] = (short)h1;
                    xl1[ks][e] = (short)f2bf(f1[e] - bf2f(h1));
                }
            }
        }

        const int it0 = cq * 4;
        uint4 peh0, peh1, pel0, pel1;
        {
            const size_t nb = (size_t)it0 * 4096;
            peh0 = *(const uint4*)(eh_g + nb + su0);
            peh1 = *(const uint4*)(eh_g + nb + su1);
            pel0 = *(const uint4*)(el_g + nb + su0);
            pel1 = *(const uint4*)(el_g + nb + su1);
            *(uint4*)&ehs[0][su0] = peh0;
            *(uint4*)&ehs[0][su1] = peh1;
            *(uint4*)&els[0][su0] = pel0;
            *(uint4*)&els[0][su1] = pel1;
        }
        __syncthreads();

        for (int ii = 0; ii < 4; ++ii) {
            const int it = it0 + ii;
            const int buf = ii & 1;
            if (ii + 1 < 4) {
                const size_t nb = (size_t)(it + 1) * 4096;
                peh0 = *(const uint4*)(eh_g + nb + su0);
                peh1 = *(const uint4*)(eh_g + nb + su1);
                pel0 = *(const uint4*)(el_g + nb + su0);
                pel1 = *(const uint4*)(el_g + nb + su1);
            }
            f32x4 a00 = {0.f,0.f,0.f,0.f}, a01 = {0.f,0.f,0.f,0.f};
            f32x4 a10 = {0.f,0.f,0.f,0.f}, a11 = {0.f,0.f,0.f,0.f};
            const unsigned short* be = &ehs[buf][0];
            const unsigned short* bl = &els[buf][0];
            #pragma unroll
            for (int ks = 0; ks < 4; ++ks) {
                short8v eA = *(const short8v*)(be + roff[ks]);
                short8v lA = *(const short8v*)(bl + roff[ks]);
                short8v eB = *(const short8v*)(be + 2048 + roff[ks]);
                short8v lB = *(const short8v*)(bl + 2048 + roff[ks]);
                a00 = __builtin_amdgcn_mfma_f32_16x16x32_bf16(eA, xh0[ks], a00, 0, 0, 0);
                a00 = __builtin_amdgcn_mfma_f32_16x16x32_bf16(lA, xh0[ks], a00, 0, 0, 0);
                a00 = __builtin_amdgcn_mfma_f32_16x16x32_bf16(eA, xl0[ks], a00, 0, 0, 0);
                a10 = __builtin_amdgcn_mfma_f32_16x16x32_bf16(eA, xh1[ks], a10, 0, 0, 0);
                a10 = __builtin_amdgcn_mfma_f32_16x16x32_bf16(lA, xh1[ks], a10, 0, 0, 0);
                a10 = __builtin_amdgcn_mfma_f32_16x16x32_bf16(eA, xl1[ks], a10, 0, 0, 0);
                a01 = __builtin_amdgcn_mfma_f32_16x16x32_bf16(eB, xh0[ks], a01, 0, 0, 0);
                a01 = __builtin_amdgcn_mfma_f32_16x16x32_bf16(lB, xh0[ks], a01, 0, 0, 0);
                a01 = __builtin_amdgcn_mfma_f32_16x16x32_bf16(eB, xl0[ks], a01, 0, 0, 0);
                a11 = __builtin_amdgcn_mfma_f32_16x16x32_bf16(eB, xh1[ks], a11, 0, 0, 0);
                a11 = __builtin_amdgcn_mfma_f32_16x16x32_bf16(lB, xh1[ks], a11, 0, 0, 0);
                a11 = __builtin_amdgcn_mfma_f32_16x16x32_bf16(eB, xl1[ks], a11, 0, 0, 0);
            }
            #pragma unroll
            for (int r = 0; r < 4; ++r) {
                int code0 = it * 32 + lg * 4 + r;
                int code1 = code0 + 16;
                float s00 = nes[code0] - 2.f * a00[r];
                float s01 = nes[code1] - 2.f * a01[r];
                float s10 = nes[code0] - 2.f * a10[r];
                float s11 = nes[code1] - 2.f * a11[r];
                if (s00 <= thr0) {
                    unsigned p = atomicAdd(&ccnt[lr0], 1u);
                    if (p < 8) ccode[lr0][p] = (unsigned)code0;
                }
                if (s01 <= thr0) {
                    unsigned p = atomicAdd(&ccnt[lr0], 1u);
                    if (p < 8) ccode[lr0][p] = (unsigned)code1;
                }
                if (s10 <= thr1) {
                    unsigned p = atomicAdd(&ccnt[lr1], 1u);
                    if (p < 8) ccode[lr1][p] = (unsigned)code0;
                }
                if (s11 <= thr1) {
                    unsigned p = atomicAdd(&ccnt[lr1], 1u);
                    if (p < 8) ccode[lr1][p] = (unsigned)code1;
                }
            }
            if (ii + 1 < 4) {
                *(uint4*)&ehs[buf ^ 1][su0] = peh0;
                *(uint4*)&ehs[buf ^ 1][su1] = peh1;
                *(uint4*)&els[buf ^ 1][su0] = pel0;
                *(uint4*)&els[buf ^ 1][su1] = pel1;
            }
            __syncthreads();
        }

        if (tid < 128) {
            int n = rid[tid];
            unsigned lc = ccnt[tid];
            if (lc > 8u) lc = 8u;
            if (n >= 0 && lc > 0) {
                unsigned p = bat * 128u + tid;
                unsigned base = atomicAdd(&cnt_g[p], lc);
                for (unsigned j = 0; j < lc; ++j) {
                    unsigned slot = base + j;
                    if (slot < 8u) cand_g[(size_t)p * 8 + slot] = ccode[tid][j];
                }
            }
        }
    }
}

// exact rescore over flagged rows (verified body) FUSED with fin_r: the last
// block (device counter) computes rcp/out_ecs, reading hist coherently via
// atomicAdd(&hist[k],0) (plain loads could hit stale per-CU L1).
__global__ __launch_bounds__(256) void krescore(
    const float* __restrict__ flat_c, const float* __restrict__ embed,
    const float* __restrict__ norm2, const float* nxg,
    const unsigned* __restrict__ flcnt, const unsigned* __restrict__ fl_list,
    const unsigned* __restrict__ cnt_g, const unsigned* __restrict__ cand_g,
    int* idx_ws, float* __restrict__ idx_out, unsigned* hist,
    unsigned* __restrict__ rdone, const float* __restrict__ ema_cs,
    float* __restrict__ out_ecs, float* __restrict__ rcp)
{
    unsigned nflag = flcnt[0];
    if (nflag > FLCAP) nflag = FLCAP;
    for (unsigned p = blockIdx.x * 256u + threadIdx.x; p < nflag;
         p += gridDim.x * 256u) {
        const int n = (int)fl_list[p];
        unsigned c = cnt_g[p];
        if (c > 8u) c = 8u;
        unsigned cc[8];
        uint4 pk0 = *(const uint4*)(cand_g + (size_t)p * 8);
        uint4 pk1 = *(const uint4*)(cand_g + (size_t)p * 8 + 4);
        cc[0] = pk0.x; cc[1] = pk0.y; cc[2] = pk0.z; cc[3] = pk0.w;
        cc[4] = pk1.x; cc[5] = pk1.y; cc[6] = pk1.z; cc[7] = pk1.w;
        int bestk = (int)cc[0];
        if (c > 1) {
            float bests = 3.4e38f;
            bestk = 1 << 30;
            const float* xr = flat_c + (size_t)n * DIM;
            const float nx = nxg[n];
            #pragma unroll
            for (int q = 0; q < 8; ++q) {
                if (q < (int)c) {
                    int k = (int)cc[q];
                    const float* er = embed + (size_t)k * DIM;
                    float dot = 0.f;
                    #pragma unroll
                    for (int d4 = 0; d4 < 32; ++d4) {
                        float4 e4 = *(const float4*)(er + d4 * 4);
                        float4 x4 = *(const float4*)(xr + d4 * 4);
                        dot = fmaf(x4.x, e4.x, dot);
                        dot = fmaf(x4.y, e4.y, dot);
                        dot = fmaf(x4.z, e4.z, dot);
                        dot = fmaf(x4.w, e4.w, dot);
                    }
                    float qv = __fadd_rn(nx, norm2[k]);
                    float s = __fsub_rn(qv, __fmul_rn(2.f, dot));
                    if (s < bests || (s == bests && k < bestk)) { bests = s; bestk = k; }
                }
            }
        }
        idx_ws[n] = bestk;
        idx_out[n] = (float)bestk;
        atomicAdd(&hist[bestk], 1u);
    }
    // last-block fin_r
    __shared__ unsigned lastv;
    __threadfence();
    if (threadIdx.x == 0) lastv = atomicAdd(rdone, 1u);
    __syncthreads();
    if (lastv == gridDim.x - 1) {
        const int tid = threadIdx.x;
        __shared__ float wsum[4];
        float local = 0.f;
        float necs[4];
        #pragma unroll
        for (int u = 0; u < 4; ++u) {
            int k = u * 256 + tid;
            unsigned h = atomicAdd(&hist[k], 0u);   // coherent read
            necs[u] = DECAY * ema_cs[k] + OMD * (float)h;
            out_ecs[k] = necs[u];
            local += necs[u];
        }
        #pragma unroll
        for (int off = 32; off >= 1; off >>= 1) local += __shfl_xor(local, off, 64);
        if ((tid & 63) == 0) wsum[tid >> 6] = local;
        __syncthreads();
        float ntot = wsum[0] + wsum[1] + wsum[2] + wsum[3];
        #pragma unroll
        for (int u = 0; u < 4; ++u) {
            int k = u * 256 + tid;
            float cs = (necs[u] + EPS) / (ntot + (float)K_CODES * EPS) * ntot;
            rcp[k] = 1.f / cs;
        }
    }
}

// FUSED tail (r18-verified) + last-quant-block writes final loss.
__global__ __launch_bounds__(512) void ktail(
    const float* __restrict__ ze, const float* __restrict__ embed,
    const int* __restrict__ idx_ws, float* __restrict__ qout,
    float* loss_acc, const float* __restrict__ flat_c,
    const float* __restrict__ ema_w, const float* __restrict__ rcp,
    float* __restrict__ out_emb, float* __restrict__ out_emaw,
    unsigned* __restrict__ qdone, float* __restrict__ loss_out)
{
    __shared__ float shmem[64 * 133];
    __shared__ int idxs[64];
    __shared__ float lsum[8];
    const int tid = threadIdx.x;
    const int bid = blockIdx.x;
    if (bid < 1024) {
        const int n0 = bid * 64;
        const int b = n0 >> 10;
        const int hw0 = n0 & (HW - 1);
        if (tid < 64) idxs[tid] = idx_ws[n0 + tid];
        __syncthreads();
        #pragma unroll
        for (int it = 0; it < 4; ++it) {
            int lin = it * 512 + tid;
            int r = lin >> 5, c4 = lin & 31;
            float4 v = *(const float4*)(embed + (size_t)idxs[r] * DIM + c4 * 4);
            *(float4*)&shmem[r * 133 + c4 * 4] = v;
        }
        __syncthreads();
        const float* zb = ze + (size_t)b * (DIM * HW) + hw0;
        float* qb = qout + (size_t)b * (DIM * HW) + hw0;
        const int hwl = tid & 63;
        float lacc = 0.f;
        #pragma unroll 4
        for (int dd = 0; dd < 16; ++dd) {
            int d = dd * 8 + (tid >> 6);
            float val = shmem[hwl * 133 + d];
            size_t off = (size_t)d * HW + hwl;
            float z = zb[off];
            qb[off] = val;
            float diff = val - z;
            lacc = fmaf(diff, diff, lacc);
        }
        #pragma unroll
        for (int off = 32; off >= 1; off >>= 1) lacc += __shfl_xor(lacc, off, 64);
        if ((tid & 63) == 0) lsum[tid >> 6] = lacc;
        __syncthreads();
        if (tid == 0) {
            float s = ((lsum[0] + lsum[1]) + (lsum[2] + lsum[3]))
                    + ((lsum[4] + lsum[5]) + (lsum[6] + lsum[7]));
            atomicAdd(loss_acc, s);
            __threadfence();
            unsigned old = atomicAdd(qdone, 1u);
            if (old == 1023u) {
                float tot = atomicAdd(loss_acc, 0.f);   // coherent read
                loss_out[0] = tot * (CCOEF / (float)((size_t)NTOT * DIM));
            }
        }
    } else {
        float (*part)[128] = (float(*)[128])shmem;
        const int k = bid - 1024;
        const int lane = tid & 63;
        const int w = tid >> 6;
        float lo = 0.f, hi = 0.f;
        const int nbeg = w * (NTOT / 8);
        const int nend = nbeg + (NTOT / 8);
        for (int base = nbeg; base < nend; base += 64) {
            int my = idx_ws[base + lane];
            unsigned long long m = __ballot(my == k);
            while (m) {
                int bit = __ffsll((long long)m) - 1;
                m &= m - 1;
                const float* row = flat_c + (size_t)(base + bit) * DIM;
                lo += row[lane];
                hi += row[lane + 64];
            }
        }
        part[w][lane] = lo;
        part[w][lane + 64] = hi;
        __syncthreads();
        if (w == 0) {
            float a = part[0][lane], bsum = part[0][lane + 64];
            #pragma unroll
            for (int u = 1; u < 8; ++u) {
                a += part[u][lane];
                bsum += part[u][lane + 64];
            }
            const float r = rcp[k];
            int elo = k * DIM + lane, ehi = elo + 64;
            float nwa = DECAY * ema_w[elo] + OMD * a;
            float nwb = DECAY * ema_w[ehi] + OMD * bsum;
            out_emaw[elo] = nwa;
            out_emaw[ehi] = nwb;
            out_emb[elo] = nwa * r;
            out_emb[ehi] = nwb * r;
        }
    }
}

// ---- fallback-only kernels (verified exact path) ----
__global__ __launch_bounds__(256, 2) void kargmin(
    const float* __restrict__ ze, const float* __restrict__ embed,
    const float* __restrict__ norm2, const float* nxg,
    int* idx_ws, float* __restrict__ idx_out,
    unsigned int* __restrict__ hist)
{
    __shared__ float xs[128 * 36];
    __shared__ float es[128 * 36];
    __shared__ float nxs[128];
    const int tid = threadIdx.x;
    const int tx = tid & 15, ty = tid >> 4;
    const int n0 = blockIdx.x * 128;
    const float* zbase = ze + (size_t)(n0 >> 10) * (DIM * HW) + (n0 & (HW - 1));
    if (tid < 128) nxs[tid] = nxg[n0 + tid];
    float minv[8];
    int   mini[8];
    #pragma unroll
    for (int i = 0; i < 8; ++i) { minv[i] = 3.4e38f; mini[i] = 0; }
    for (int kt = 0; kt < 8; ++kt) {
        float acc[8][8];
        #pragma unroll
        for (int i = 0; i < 8; ++i)
            #pragma unroll
            for (int j = 0; j < 8; ++j) acc[i][j] = 0.f;
        for (int dc = 0; dc < 4; ++dc) {
            __syncthreads();
            #pragma unroll
            for (int it = 0; it < 4; ++it) {
                int lin = it * 256 + tid;
                int r  = lin & 127;
                int gu = lin >> 7;
                const float* gp = zbase + (size_t)(dc * 32 + gu * 4) * HW + r;
                float4 v;
                v.x = gp[0]; v.y = gp[HW]; v.z = gp[2 * HW]; v.w = gp[3 * HW];
                *(float4*)&xs[r * 36 + gu * 4] = v;
            }
            #pragma unroll
            for (int it = 0; it < 4; ++it) {
                int lin = it * 256 + tid;
                int k  = lin >> 3;
                int gu = lin & 7;
                float4 v = *(const float4*)(embed + (size_t)(kt * 128 + k) * DIM + dc * 32 + gu * 4);
                *(float4*)&es[k * 36 + gu * 4] = v;
            }
            __syncthreads();
            #pragma unroll
            for (int g = 0; g < 8; ++g) {
                float4 xf[8];
                #pragma unroll
                for (int i = 0; i < 8; ++i)
                    xf[i] = *(const float4*)&xs[(ty + i * 16) * 36 + g * 4];
                #pragma unroll
                for (int j = 0; j < 8; ++j) {
                    float4 ef = *(const float4*)&es[(tx + j * 16) * 36 + g * 4];
                    #pragma unroll
                    for (int i = 0; i < 8; ++i) {
                        acc[i][j] = fmaf(xf[i].x, ef.x, acc[i][j]);
                        acc[i][j] = fmaf(xf[i].y, ef.y, acc[i][j]);
                        acc[i][j] = fmaf(xf[i].z, ef.z, acc[i][j]);
                        acc[i][j] = fmaf(xf[i].w, ef.w, acc[i][j]);
                    }
                }
            }
        }
        #pragma unroll
        for (int j = 0; j < 8; ++j) {
            int kg = kt * 128 + tx + j * 16;
            float nrm = norm2[kg];
            #pragma unroll
            for (int i = 0; i < 8; ++i) {
                float q = __fadd_rn(nxs[ty + i * 16], nrm);
                float t = __fmul_rn(2.f, acc[i][j]);
                float s = __fsub_rn(q, t);
                if (s < minv[i]) { minv[i] = s; mini[i] = kg; }
            }
        }
    }
    #pragma unroll
    for (int i = 0; i < 8; ++i) {
        float v = minv[i]; int ix = mini[i];
        #pragma unroll
        for (int off = 8; off >= 1; off >>= 1) {
            float v2 = __shfl_xor(v, off, 16);
            int   i2 = __shfl_xor(ix, off, 16);
            if (v2 < v || (v2 == v && i2 < ix)) { v = v2; ix = i2; }
        }
        if (tx == 0) {
            int n = n0 + ty + i * 16;
            idx_ws[n] = ix;
            idx_out[n] = (float)ix;
            atomicAdd(&hist[ix], 1u);
        }
    }
}

__global__ __launch_bounds__(256) void kquant(
    const float* __restrict__ ze, const float* __restrict__ embed,
    const int* __restrict__ idx_ws, float* __restrict__ qout,
    float* __restrict__ dw_atomic, float* __restrict__ loss_acc)
{
    __shared__ float q[128 * 133];
    __shared__ int idxs[128];
    __shared__ float lsum[4];
    const int tid = threadIdx.x;
    const int n0 = blockIdx.x * 128;
    const int b = n0 >> 10;
    const int hw0 = n0 & (HW - 1);
    if (tid < 128) idxs[tid] = idx_ws[n0 + tid];
    __syncthreads();
    #pragma unroll
    for (int it = 0; it < 16; ++it) {
        int r = it * 8 + (tid >> 5);
        int c = tid & 31;
        float4 v = *(const float4*)(embed + (size_t)idxs[r] * DIM + c * 4);
        *(float4*)&q[r * 133 + c * 4] = v;
    }
    __syncthreads();
    const float* zb = ze + (size_t)b * (DIM * HW) + hw0;
    float* qb = qout + (size_t)b * (DIM * HW) + hw0;
    float lacc = 0.f;
    for (int dd = 0; dd < 64; ++dd) {
        int d = dd * 2 + (tid >> 7);
        int hw = tid & 127;
        float val = q[hw * 133 + d];
        size_t off = (size_t)d * HW + hw;
        float z = zb[off];
        qb[off] = val;
        float diff = val - z;
        lacc = fmaf(diff, diff, lacc);
        if (dw_atomic) atomicAdd(&dw_atomic[idxs[hw] * DIM + d], z);
    }
    #pragma unroll
    for (int off = 32; off >= 1; off >>= 1) lacc += __shfl_xor(lacc, off, 64);
    if ((tid & 63) == 0) lsum[tid >> 6] = lacc;
    __syncthreads();
    if (tid == 0) atomicAdd(loss_acc, lsum[0] + lsum[1] + lsum[2] + lsum[3]);
}

__global__ __launch_bounds__(256) void kfin1(
    const unsigned int* __restrict__ hist, const float* __restrict__ ema_cs,
    float* __restrict__ out_ecs, float* __restrict__ rcp,
    float* __restrict__ loss_out, const float* __restrict__ loss_acc)
{
    const int tid = threadIdx.x;
    __shared__ float wsum[4];
    float local = 0.f;
    float necs[4];
    #pragma unroll
    for (int u = 0; u < 4; ++u) {
        int k = u * 256 + tid;
        necs[u] = DECAY * ema_cs[k] + OMD * (float)hist[k];
        out_ecs[k] = necs[u];
        local += necs[u];
    }
    #pragma unroll
    for (int off = 32; off >= 1; off >>= 1) local += __shfl_xor(local, off, 64);
    if ((tid & 63) == 0) wsum[tid >> 6] = local;
    __syncthreads();
    float ntot = wsum[0] + wsum[1] + wsum[2] + wsum[3];
    #pragma unroll
    for (int u = 0; u < 4; ++u) {
        int k = u * 256 + tid;
        float cs = (necs[u] + EPS) / (ntot + (float)K_CODES * EPS) * ntot;
        rcp[k] = 1.f / cs;
    }
    if (tid == 0) loss_out[0] = loss_acc[0] * (CCOEF / (float)((size_t)NTOT * DIM));
}

__global__ __launch_bounds__(256) void kfin2(
    const float* __restrict__ ema_w, const float* __restrict__ dw,
    const float* __restrict__ rcp, float* __restrict__ out_emb,
    float* __restrict__ out_emaw)
{
    int e = blockIdx.x * 256 + threadIdx.x;
    int k = e >> 7;
    float nw = DECAY * ema_w[e] + OMD * dw[e];
    out_emaw[e] = nw;
    out_emb[e] = nw * rcp[k];
}

extern "C" void kernel_launch(void* const* d_in, const int* in_sizes, int n_in,
                              void* d_out, int out_size, void* d_ws, size_t ws_size,
                              hipStream_t stream) {
    const float* ze     = (const float*)d_in[0];
    const float* embed  = (const float*)d_in[1];
    const float* ema_cs = (const float*)d_in[2];
    const float* ema_w  = (const float*)d_in[3];
    float* out = (float*)d_out;

    float* ws = (float*)d_ws;
    float*          ws_norm2 = ws + W_NORM2;
    float*          ws_rcp   = ws + W_RCP;
    unsigned*       ws_hist  = (unsigned*)(ws + W_HIST);
    float*          ws_loss  = ws + W_LOSS;
    unsigned*       ws_flcnt = (unsigned*)(ws + W_FLCNT);
    unsigned*       ws_rdone = (unsigned*)(ws + W_RDONE);
    unsigned*       ws_qdone = (unsigned*)(ws + W_QDONE);
    unsigned*       ws_cnt   = (unsigned*)(ws + W_CNT2);
    unsigned*       ws_fl    = (unsigned*)(ws + W_FL);
    float*          ws_m1    = ws + W_M1F;
    unsigned*       ws_cand  = (unsigned*)(ws + W_CAND);
    float*          ws_dw    = ws + W_CAND;                // fallback alias
    unsigned short* ws_eh    = (unsigned short*)(ws + W_EH);
    unsigned short* ws_el    = (unsigned short*)(ws + W_EL);
    float*          ws_nx    = ws + W_NXIDX;               // aliased with idx
    int*            ws_idx   = (int*)(ws + W_NXIDX);
    float*          ws_flat  = ws + W_FLAT;
    const size_t need = (size_t)W_NEED * sizeof(float);
    const bool big_ws = ws_size >= need;

    if (big_ws) {
        hipLaunchKernelGGL(kpre, dim3(640), dim3(256), 0, stream,
                           ze, ws_nx, ws_flat, embed, ws_norm2, ws_eh, ws_el,
                           (float*)ws_hist, 25604);
        hipLaunchKernelGGL(kapprox, dim3(1024), dim3(256), 0, stream,
                           ws_flat, ws_eh, ws_el, ws_norm2,
                           ws_idx, out + OFF_IDX, ws_hist, ws_flcnt, ws_fl, ws_m1);
        hipLaunchKernelGGL(kapprox2, dim3(512), dim3(256), 0, stream,
                           ws_flat, ws_eh, ws_el, ws_norm2,
                           ws_m1, ws_flcnt, ws_fl, ws_cnt, ws_cand);
        hipLaunchKernelGGL(krescore, dim3(64), dim3(256), 0, stream,
                           ws_flat, embed, ws_norm2, ws_nx, ws_flcnt, ws_fl,
                           ws_cnt, ws_cand, ws_idx, out + OFF_IDX, ws_hist,
                           ws_rdone, ema_cs, out + OFF_ECS, ws_rcp);
        hipLaunchKernelGGL(ktail, dim3(2048), dim3(512), 0, stream,
                           ze, embed, ws_idx, out + OFF_Q, ws_loss,
                           ws_flat, ema_w, ws_rcp, out + OFF_EMB, out + OFF_EMAW,
                           ws_qdone, out + OFF_LOSS);
    } else {
        hipLaunchKernelGGL(kpre, dim3(640), dim3(256), 0, stream,
                           ze, ws_nx, (float*)nullptr, embed, ws_norm2,
                           (unsigned short*)nullptr, (unsigned short*)nullptr,
                           (float*)ws_hist, 1028);
        hipLaunchKernelGGL(kzero, dim3(512), dim3(256), 0, stream, ws_dw, 131072);
        hipLaunchKernelGGL(kargmin, dim3(512), dim3(256), 0, stream,
                           ze, embed, ws_norm2, ws_nx, ws_idx, out + OFF_IDX, ws_hist);
        hipLaunchKernelGGL(kquant, dim3(512), dim3(256), 0, stream,
                           ze, embed, ws_idx, out + OFF_Q, ws_dw, ws_loss);
        hipLaunchKernelGGL(kfin1, dim3(1), dim3(256), 0, stream,
                           ws_hist, ema_cs, out + OFF_ECS, ws_rcp, out + OFF_LOSS, ws_loss);
        hipLaunchKernelGGL(kfin2, dim3(512), dim3(256), 0, stream,
                           ema_w, ws_dw, ws_rcp, out + OFF_EMB, out + OFF_EMAW);
    }
}

// Round 20
// 168.621 us; speedup vs baseline: 1.1910x; 1.1910x over previous
//
#include <hip/hip_runtime.h>

#define K_CODES 1024
#define DIM 128
#define HW 1024
#define NTOT 65536
#define DECAY 0.99f
#define OMD 0.01f
#define EPS 1e-5f
#define CCOEF 0.25f
#define MARGIN 1e-4f
#define FLCAP 24576

// d_out offsets (floats)
#define OFF_Q    0
#define OFF_IDX  8388608
#define OFF_LOSS (8388608 + 65536)
#define OFF_EMB  (OFF_LOSS + 1)
#define OFF_ECS  (OFF_EMB + 131072)
#define OFF_EMAW (OFF_ECS + 1024)

// workspace layout (word offsets); hist..cnt contiguous for one zero pass
#define W_NORM2 0
#define W_RCP   1024
#define W_HIST  2048
#define W_LOSS  3072
#define W_FLCNT 3073
#define W_CNT2  3076
#define W_FL    (3076 + 24576)
#define W_M1F   (27652 + 24576)
#define W_CAND  (52228 + 24576)
#define W_EH    (76804 + 196608)       // 273412 (PRE-SWIZZLED layout)
#define W_EL    (273412 + 65536)       // 338948
#define W_NXIDX (338948 + 65536)       // 404484
#define W_FLAT  (404484 + 65536)       // 470020
#define W_NEED  (470020 + 8388608)

typedef __attribute__((ext_vector_type(8))) short short8v;
typedef __attribute__((ext_vector_type(4))) float f32x4;

__device__ __forceinline__ unsigned short f2bf(float f) {
    unsigned u = __float_as_uint(f);
    u += 0x7fffu + ((u >> 16) & 1u);
    return (unsigned short)(u >> 16);
}
__device__ __forceinline__ float bf2f(unsigned short h) {
    return __uint_as_float(((unsigned)h) << 16);
}

__global__ __launch_bounds__(256) void kzero(float* __restrict__ p, int n) {
    int i = blockIdx.x * 256 + threadIdx.x;
    if (i < n) p[i] = 0.f;
}

// numpy pairwise_sum replica (per-thread form) — verified.
__device__ __forceinline__ float np_pairwise_sumsq_128(const float* p, size_t stride) {
    float r[8][4];
    #pragma unroll
    for (int j = 0; j < 8; ++j)
        #pragma unroll
        for (int L = 0; L < 4; ++L) {
            float x = p[(size_t)(j * 4 + L) * stride];
            r[j][L] = __fmul_rn(x, x);
        }
    #pragma unroll
    for (int c = 1; c < 4; ++c)
        #pragma unroll
        for (int j = 0; j < 8; ++j)
            #pragma unroll
            for (int L = 0; L < 4; ++L) {
                float x = p[(size_t)(c * 32 + j * 4 + L) * stride];
                r[j][L] = __fadd_rn(r[j][L], __fmul_rn(x, x));
            }
    float V[4];
    #pragma unroll
    for (int L = 0; L < 4; ++L) {
        float a = __fadd_rn(r[0][L], r[1][L]);
        float b = __fadd_rn(r[2][L], r[3][L]);
        float c2 = __fadd_rn(r[4][L], r[5][L]);
        float d2 = __fadd_rn(r[6][L], r[7][L]);
        V[L] = __fadd_rn(__fadd_rn(a, b), __fadd_rn(c2, d2));
    }
    return __fadd_rn(__fadd_rn(V[0], V[1]), __fadd_rn(V[2], V[3]));
}

// FUSED preprocessing: blocks 0..511 = knx body (transpose+nx+flat_c);
// blocks 512..639 = kprep body (zero accumulators + norm2 wave-coop pairwise
// [bit-identical tree] + bf16 hi/lo split written PRE-SWIZZLED).
__global__ __launch_bounds__(256) void kpre(
    const float* __restrict__ ze, float* __restrict__ nx,
    float* __restrict__ flat_c, const float* __restrict__ embed,
    float* __restrict__ norm2, unsigned short* __restrict__ ehs_g,
    unsigned short* __restrict__ els_g, float* __restrict__ zero_p, int zero_n)
{
    __shared__ float t[128][133];
    const int tid = threadIdx.x;
    const int bid = blockIdx.x;
    if (bid < 512) {
        const int n0 = bid * 128;
        const int b = n0 >> 10, hw0 = n0 & (HW - 1);
        const float* zb = ze + (size_t)b * (DIM * HW) + hw0;
        #pragma unroll
        for (int i = 0; i < 64; ++i) {
            int d = i * 2 + (tid >> 7);
            int hw = tid & 127;
            t[hw][d] = zb[(size_t)d * HW + hw];
        }
        __syncthreads();
        if (tid < 128) nx[n0 + tid] = np_pairwise_sumsq_128(&t[tid][0], 1);
        if (flat_c) {
            #pragma unroll
            for (int i = 0; i < 16; ++i) {
                int lin = i * 256 + tid;
                int r  = lin >> 5;
                int c4 = lin & 31;
                float4 v = *(const float4*)&t[r][c4 * 4];
                *(float4*)&flat_c[(size_t)(n0 + r) * DIM + c4 * 4] = v;
            }
        }
    } else {
        const int pid = bid - 512;
        int zi = pid * 256 + tid;
        if (zi < zero_n) zero_p[zi] = 0.f;
        {
            const int g32 = tid >> 5, l32 = tid & 31;
            const int k = pid * 8 + g32;
            const float* row = embed + (size_t)k * DIM;
            float x = row[l32];
            float r = __fmul_rn(x, x);
            #pragma unroll
            for (int c = 1; c < 4; ++c) {
                float y = row[c * 32 + l32];
                r = __fadd_rn(r, __fmul_rn(y, y));
            }
            float s1 = __fadd_rn(r, __shfl_xor(r, 4, 64));
            float s2 = __fadd_rn(s1, __shfl_xor(s1, 8, 64));
            float s3 = __fadd_rn(s2, __shfl_xor(s2, 16, 64));
            float h1 = __fadd_rn(s3, __shfl_xor(s3, 1, 64));
            float h2 = __fadd_rn(h1, __shfl_xor(h1, 2, 64));
            if (l32 == 0) norm2[k] = h2;
        }
        if (ehs_g) {
            int hu = pid * 256 + tid;
            int U = hu >> 1, half = hu & 1;
            int code = U >> 4;
            int g = (U & 15) ^ (code & 15);
            const float* src = embed + (size_t)code * DIM + g * 8 + half * 4;
            float4 f = *(const float4*)src;
            unsigned short a = f2bf(f.x), b = f2bf(f.y), c = f2bf(f.z), d = f2bf(f.w);
            ushort4 hi; hi.x = a; hi.y = b; hi.z = c; hi.w = d;
            ushort4 lo;
            lo.x = f2bf(f.x - bf2f(a)); lo.y = f2bf(f.y - bf2f(b));
            lo.z = f2bf(f.z - bf2f(c)); lo.w = f2bf(f.w - bf2f(d));
            *(ushort4*)(ehs_g + (size_t)U * 8 + half * 4) = hi;
            *(ushort4*)(els_g + (size_t)U * 8 + half * 4) = lo;
        }
    }
}

// bf16x3 MFMA single-pass argmin (r17-verified, byte-identical).
__global__ __launch_bounds__(256, 4) void kapprox(
    const float* __restrict__ flat_c, const unsigned short* __restrict__ eh_g,
    const unsigned short* __restrict__ el_g, const float* __restrict__ norm2,
    int* __restrict__ idx_ws, float* __restrict__ idx_out,
    unsigned* __restrict__ hist, unsigned* __restrict__ flcnt,
    unsigned* __restrict__ fl_list, float* __restrict__ m1f)
{
    __shared__ __align__(16) unsigned short ehs[2][32 * 128];
    __shared__ __align__(16) unsigned short els[2][32 * 128];
    __shared__ float nes[1024];

    const int tid = threadIdx.x;
    const int l = tid & 63;
    const int w = tid >> 6;
    const int lg = l >> 4;
    const int lm = l & 15;
    const int n0 = blockIdx.x * 64;

    for (int i = tid; i < 1024; i += 256) nes[i] = norm2[i];

    short8v xh[4], xl[4];
    {
        const float* xr = flat_c + (size_t)(n0 + w * 16 + lm) * DIM;
        #pragma unroll
        for (int ks = 0; ks < 4; ++ks) {
            int kb = ks * 32 + lg * 8;
            float f0[8];
            *(float4*)&f0[0] = *(const float4*)(xr + kb);
            *(float4*)&f0[4] = *(const float4*)(xr + kb + 4);
            #pragma unroll
            for (int e = 0; e < 8; ++e) {
                unsigned short h0 = f2bf(f0[e]);
                xh[ks][e] = (short)h0;
                xl[ks][e] = (short)f2bf(f0[e] - bf2f(h0));
            }
        }
    }

    int roff[4];
    #pragma unroll
    for (int ks = 0; ks < 4; ++ks)
        roff[ks] = lm * 128 + (((ks * 4 + lg) ^ lm) * 8);

    const int su0 = tid * 8;
    const int su1 = 2048 + tid * 8;

    uint4 peh0 = *(const uint4*)(eh_g + su0);
    uint4 peh1 = *(const uint4*)(eh_g + su1);
    uint4 pel0 = *(const uint4*)(el_g + su0);
    uint4 pel1 = *(const uint4*)(el_g + su1);
    *(uint4*)&ehs[0][su0] = peh0;
    *(uint4*)&ehs[0][su1] = peh1;
    *(uint4*)&els[0][su0] = pel0;
    *(uint4*)&els[0][su1] = pel1;
    __syncthreads();

    float m1 = 3.4e38f, m2 = 3.4e38f;
    int c1 = 0;

    for (int it = 0; it < 32; ++it) {
        const int buf = it & 1;
        const int nt = it + 1;
        if (nt < 32) {
            const size_t nb = (size_t)nt * 4096;
            peh0 = *(const uint4*)(eh_g + nb + su0);
            peh1 = *(const uint4*)(eh_g + nb + su1);
            pel0 = *(const uint4*)(el_g + nb + su0);
            pel1 = *(const uint4*)(el_g + nb + su1);
        }
        f32x4 a00 = {0.f,0.f,0.f,0.f}, a01 = {0.f,0.f,0.f,0.f};
        const unsigned short* be = &ehs[buf][0];
        const unsigned short* bl = &els[buf][0];
        #pragma unroll
        for (int ks = 0; ks < 4; ++ks) {
            short8v eA = *(const short8v*)(be + roff[ks]);
            short8v lA = *(const short8v*)(bl + roff[ks]);
            short8v eB = *(const short8v*)(be + 2048 + roff[ks]);
            short8v lB = *(const short8v*)(bl + 2048 + roff[ks]);
            a00 = __builtin_amdgcn_mfma_f32_16x16x32_bf16(eA, xh[ks], a00, 0, 0, 0);
            a00 = __builtin_amdgcn_mfma_f32_16x16x32_bf16(lA, xh[ks], a00, 0, 0, 0);
            a00 = __builtin_amdgcn_mfma_f32_16x16x32_bf16(eA, xl[ks], a00, 0, 0, 0);
            a01 = __builtin_amdgcn_mfma_f32_16x16x32_bf16(eB, xh[ks], a01, 0, 0, 0);
            a01 = __builtin_amdgcn_mfma_f32_16x16x32_bf16(lB, xh[ks], a01, 0, 0, 0);
            a01 = __builtin_amdgcn_mfma_f32_16x16x32_bf16(eB, xl[ks], a01, 0, 0, 0);
        }
        #pragma unroll
        for (int r = 0; r < 4; ++r) {
            int code0 = it * 32 + lg * 4 + r;
            int code1 = code0 + 16;
            float s0 = nes[code0] - 2.f * a00[r];
            float s1 = nes[code1] - 2.f * a01[r];
            m2 = fminf(m2, fmaxf(m1, s0));
            if (s0 < m1) { m1 = s0; c1 = code0; }
            m2 = fminf(m2, fmaxf(m1, s1));
            if (s1 < m1) { m1 = s1; c1 = code1; }
        }
        if (nt < 32) {
            *(uint4*)&ehs[buf ^ 1][su0] = peh0;
            *(uint4*)&ehs[buf ^ 1][su1] = peh1;
            *(uint4*)&els[buf ^ 1][su0] = pel0;
            *(uint4*)&els[buf ^ 1][su1] = pel1;
        }
        __syncthreads();
    }

    #pragma unroll
    for (int mk = 16; mk <= 32; mk <<= 1) {
        float om1 = __shfl_xor(m1, mk, 64);
        int   oc1 = __shfl_xor(c1, mk, 64);
        float om2 = __shfl_xor(m2, mk, 64);
        m2 = fminf(fminf(m2, om2), fmaxf(m1, om1));
        if (om1 < m1 || (om1 == m1 && oc1 < c1)) { m1 = om1; c1 = oc1; }
    }
    if (lg == 0) {
        int n = n0 + w * 16 + lm;
        if (m2 - m1 > MARGIN) {
            idx_ws[n] = c1;
            idx_out[n] = (float)c1;
            atomicAdd(&hist[c1], 1u);
        } else {
            unsigned p = atomicAdd(flcnt, 1u);
            if (p < FLCAP) { fl_list[p] = (unsigned)n; m1f[p] = m1; }
            else {
                idx_ws[n] = c1; idx_out[n] = (float)c1;
                atomicAdd(&hist[c1], 1u);
            }
        }
    }
}

// candidate collection, WIDE (r17-verified, byte-identical).
__global__ __launch_bounds__(256, 2) void kapprox2(
    const float* __restrict__ flat_c, const unsigned short* __restrict__ eh_g,
    const unsigned short* __restrict__ el_g, const float* __restrict__ norm2,
    const float* __restrict__ m1f, const unsigned* __restrict__ flcnt,
    const unsigned* __restrict__ fl_list, unsigned* __restrict__ cnt_g,
    unsigned* __restrict__ cand_g)
{
    __shared__ __align__(16) unsigned short ehs[2][32 * 128];
    __shared__ __align__(16) unsigned short els[2][32 * 128];
    __shared__ float nes[1024];
    __shared__ unsigned ccnt[128];
    __shared__ unsigned ccode[128][8];
    __shared__ int rid[128];
    __shared__ float thrs[128];

    const int tid = threadIdx.x;
    const int l = tid & 63;
    const int w = tid >> 6;
    const int lg = l >> 4;
    const int lm = l & 15;

    for (int i = tid; i < 1024; i += 256) nes[i] = norm2[i];

    int roff[4];
    #pragma unroll
    for (int ks = 0; ks < 4; ++ks)
        roff[ks] = lm * 128 + (((ks * 4 + lg) ^ lm) * 8);

    const int su0 = tid * 8;
    const int su1 = 2048 + tid * 8;

    unsigned nflag = flcnt[0];
    if (nflag > FLCAP) nflag = FLCAP;
    const unsigned nbat = (nflag + 127u) >> 7;
    const unsigned nwork = nbat * 8u;

    for (unsigned wi = blockIdx.x; wi < nwork; wi += gridDim.x) {
        const unsigned bat = wi >> 3;
        const int cq = (int)(wi & 7u);
        __syncthreads();
        if (tid < 128) {
            unsigned p = bat * 128u + tid;
            int n = (p < nflag) ? (int)fl_list[p] : -1;
            rid[tid] = n;
            thrs[tid] = (n >= 0) ? m1f[p] + MARGIN : -3.4e38f;
            ccnt[tid] = 0;
        }
        __syncthreads();

        const int lr0 = w * 32 + lm, lr1 = lr0 + 16;
        const int nr0 = rid[lr0], nr1 = rid[lr1];
        const float thr0 = thrs[lr0], thr1 = thrs[lr1];
        short8v xh0[4], xl0[4], xh1[4], xl1[4];
        {
            const float* xr0 = flat_c + (size_t)(nr0 < 0 ? 0 : nr0) * DIM;
            const float* xr1 = flat_c + (size_t)(nr1 < 0 ? 0 : nr1) * DIM;
            #pragma unroll
            for (int ks = 0; ks < 4; ++ks) {
                int kb = ks * 32 + lg * 8;
                float f0[8], f1[8];
                *(float4*)&f0[0] = *(const float4*)(xr0 + kb);
                *(float4*)&f0[4] = *(const float4*)(xr0 + kb + 4);
                *(float4*)&f1[0] = *(const float4*)(xr1 + kb);
                *(float4*)&f1[4] = *(const float4*)(xr1 + kb + 4);
                #pragma unroll
                for (int e = 0; e < 8; ++e) {
                    unsigned short h0 = f2bf(f0[e]);
                    unsigned short h1 = f2bf(f1[e]);
                    xh0[ks][e] = (short)h0;
                    xl0[ks][e] = (short)f2bf(f0[e] - bf2f(h0));
                    xh1[ks][e] = (short)h1;
                    xl1[ks][e] = (short)f2bf(f1[e] - bf2f(h1));
                }
            }
        }

        const int it0 = cq * 4;
        uint4 peh0, peh1, pel0, pel1;
        {
            const size_t nb = (size_t)it0 * 4096;
            peh0 = *(const uint4*)(eh_g + nb + su0);
            peh1 = *(const uint4*)(eh_g + nb + su1);
            pel0 = *(const uint4*)(el_g + nb + su0);
            pel1 = *(const uint4*)(el_g + nb + su1);
            *(uint4*)&ehs[0][su0] = peh0;
            *(uint4*)&ehs[0][su1] = peh1;
            *(uint4*)&els[0][su0] = pel0;
            *(uint4*)&els[0][su1] = pel1;
        }
        __syncthreads();

        for (int ii = 0; ii < 4; ++ii) {
            const int it = it0 + ii;
            const int buf = ii & 1;
            if (ii + 1 < 4) {
                const size_t nb = (size_t)(it + 1) * 4096;
                peh0 = *(const uint4*)(eh_g + nb + su0);
                peh1 = *(const uint4*)(eh_g + nb + su1);
                pel0 = *(const uint4*)(el_g + nb + su0);
                pel1 = *(const uint4*)(el_g + nb + su1);
            }
            f32x4 a00 = {0.f,0.f,0.f,0.f}, a01 = {0.f,0.f,0.f,0.f};
            f32x4 a10 = {0.f,0.f,0.f,0.f}, a11 = {0.f,0.f,0.f,0.f};
            const unsigned short* be = &ehs[buf][0];
            const unsigned short* bl = &els[buf][0];
            #pragma unroll
            for (int ks = 0; ks < 4; ++ks) {
                short8v eA = *(const short8v*)(be + roff[ks]);
                short8v lA = *(const short8v*)(bl + roff[ks]);
                short8v eB = *(const short8v*)(be + 2048 + roff[ks]);
                short8v lB = *(const short8v*)(bl + 2048 + roff[ks]);
                a00 = __builtin_amdgcn_mfma_f32_16x16x32_bf16(eA, xh0[ks], a00, 0, 0, 0);
                a00 = __builtin_amdgcn_mfma_f32_16x16x32_bf16(lA, xh0[ks], a00, 0, 0, 0);
                a00 = __builtin_amdgcn_mfma_f32_16x16x32_bf16(eA, xl0[ks], a00, 0, 0, 0);
                a10 = __builtin_amdgcn_mfma_f32_16x16x32_bf16(eA, xh1[ks], a10, 0, 0, 0);
                a10 = __builtin_amdgcn_mfma_f32_16x16x32_bf16(lA, xh1[ks], a10, 0, 0, 0);
                a10 = __builtin_amdgcn_mfma_f32_16x16x32_bf16(eA, xl1[ks], a10, 0, 0, 0);
                a01 = __builtin_amdgcn_mfma_f32_16x16x32_bf16(eB, xh0[ks], a01, 0, 0, 0);
                a01 = __builtin_amdgcn_mfma_f32_16x16x32_bf16(lB, xh0[ks], a01, 0, 0, 0);
                a01 = __builtin_amdgcn_mfma_f32_16x16x32_bf16(eB, xl0[ks], a01, 0, 0, 0);
                a11 = __builtin_amdgcn_mfma_f32_16x16x32_bf16(eB, xh1[ks], a11, 0, 0, 0);
                a11 = __builtin_amdgcn_mfma_f32_16x16x32_bf16(lB, xh1[ks], a11, 0, 0, 0);
                a11 = __builtin_amdgcn_mfma_f32_16x16x32_bf16(eB, xl1[ks], a11, 0, 0, 0);
            }
            #pragma unroll
            for (int r = 0; r < 4; ++r) {
                int code0 = it * 32 + lg * 4 + r;
                int code1 = code0 + 16;
                float s00 = nes[code0] - 2.f * a00[r];
                float s01 = nes[code1] - 2.f * a01[r];
                float s10 = nes[code0] - 2.f * a10[r];
                float s11 = nes[code1] - 2.f * a11[r];
                if (s00 <= thr0) {
                    unsigned p = atomicAdd(&ccnt[lr0], 1u);
                    if (p < 8) ccode[lr0][p] = (unsigned)code0;
                }
                if (s01 <= thr0) {
                    unsigned p = atomicAdd(&ccnt[lr0], 1u);
                    if (p < 8) ccode[lr0][p] = (unsigned)code1;
                }
                if (s10 <= thr1) {
                    unsigned p = atomicAdd(&ccnt[lr1], 1u);
                    if (p < 8) ccode[lr1][p] = (unsigned)code0;
                }
                if (s11 <= thr1) {
                    unsigned p = atomicAdd(&ccnt[lr1], 1u);
                    if (p < 8) ccode[lr1][p] = (unsigned)code1;
                }
            }
            if (ii + 1 < 4) {
                *(uint4*)&ehs[buf ^ 1][su0] = peh0;
                *(uint4*)&ehs[buf ^ 1][su1] = peh1;
                *(uint4*)&els[buf ^ 1][su0] = pel0;
                *(uint4*)&els[buf ^ 1][su1] = pel1;
            }
            __syncthreads();
        }

        if (tid < 128) {
            int n = rid[tid];
            unsigned lc = ccnt[tid];
            if (lc > 8u) lc = 8u;
            if (n >= 0 && lc > 0) {
                unsigned p = bat * 128u + tid;
                unsigned base = atomicAdd(&cnt_g[p], lc);
                for (unsigned j = 0; j < lc; ++j) {
                    unsigned slot = base + j;
                    if (slot < 8u) cand_g[(size_t)p * 8 + slot] = ccode[tid][j];
                }
            }
        }
    }
}

// exact rescore over flagged rows (verified; set function -> deterministic).
__global__ __launch_bounds__(256) void krescore(
    const float* __restrict__ flat_c, const float* __restrict__ embed,
    const float* __restrict__ norm2, const float* nxg,
    const unsigned* __restrict__ flcnt, const unsigned* __restrict__ fl_list,
    const unsigned* __restrict__ cnt_g, const unsigned* __restrict__ cand_g,
    int* idx_ws, float* __restrict__ idx_out, unsigned* __restrict__ hist)
{
    unsigned nflag = flcnt[0];
    if (nflag > FLCAP) nflag = FLCAP;
    for (unsigned p = blockIdx.x * 256u + threadIdx.x; p < nflag;
         p += gridDim.x * 256u) {
        const int n = (int)fl_list[p];
        unsigned c = cnt_g[p];
        if (c > 8u) c = 8u;
        unsigned cc[8];
        uint4 pk0 = *(const uint4*)(cand_g + (size_t)p * 8);
        uint4 pk1 = *(const uint4*)(cand_g + (size_t)p * 8 + 4);
        cc[0] = pk0.x; cc[1] = pk0.y; cc[2] = pk0.z; cc[3] = pk0.w;
        cc[4] = pk1.x; cc[5] = pk1.y; cc[6] = pk1.z; cc[7] = pk1.w;
        int bestk = (int)cc[0];
        if (c > 1) {
            float bests = 3.4e38f;
            bestk = 1 << 30;
            const float* xr = flat_c + (size_t)n * DIM;
            const float nx = nxg[n];
            #pragma unroll
            for (int q = 0; q < 8; ++q) {
                if (q < (int)c) {
                    int k = (int)cc[q];
                    const float* er = embed + (size_t)k * DIM;
                    float dot = 0.f;
                    #pragma unroll
                    for (int d4 = 0; d4 < 32; ++d4) {
                        float4 e4 = *(const float4*)(er + d4 * 4);
                        float4 x4 = *(const float4*)(xr + d4 * 4);
                        dot = fmaf(x4.x, e4.x, dot);
                        dot = fmaf(x4.y, e4.y, dot);
                        dot = fmaf(x4.z, e4.z, dot);
                        dot = fmaf(x4.w, e4.w, dot);
                    }
                    float qv = __fadd_rn(nx, norm2[k]);
                    float s = __fsub_rn(qv, __fmul_rn(2.f, dot));
                    if (s < bests || (s == bests && k < bestk)) { bests = s; bestk = k; }
                }
            }
        }
        idx_ws[n] = bestk;
        idx_out[n] = (float)bestk;
        atomicAdd(&hist[bestk], 1u);
    }
}

// rcp + out_ecs (hist complete after krescore); no loss here.
__global__ __launch_bounds__(256) void kfin_r(
    const unsigned int* __restrict__ hist, const float* __restrict__ ema_cs,
    float* __restrict__ out_ecs, float* __restrict__ rcp)
{
    const int tid = threadIdx.x;
    __shared__ float wsum[4];
    float local = 0.f;
    float necs[4];
    #pragma unroll
    for (int u = 0; u < 4; ++u) {
        int k = u * 256 + tid;
        necs[u] = DECAY * ema_cs[k] + OMD * (float)hist[k];
        out_ecs[k] = necs[u];
        local += necs[u];
    }
    #pragma unroll
    for (int off = 32; off >= 1; off >>= 1) local += __shfl_xor(local, off, 64);
    if ((tid & 63) == 0) wsum[tid >> 6] = local;
    __syncthreads();
    float ntot = wsum[0] + wsum[1] + wsum[2] + wsum[3];
    #pragma unroll
    for (int u = 0; u < 4; ++u) {
        int k = u * 256 + tid;
        float cs = (necs[u] + EPS) / (ntot + (float)K_CODES * EPS) * ntot;
        rcp[k] = 1.f / cs;
    }
}

__global__ __launch_bounds__(64) void kloss(
    float* __restrict__ loss_out, const float* __restrict__ loss_acc)
{
    if (threadIdx.x == 0)
        loss_out[0] = loss_acc[0] * (CCOEF / (float)((size_t)NTOT * DIM));
}

// FUSED tail: blocks 0..1023 = kquant64; blocks 1024..2047 = kdwf.
__global__ __launch_bounds__(512) void ktail(
    const float* __restrict__ ze, const float* __restrict__ embed,
    const int* __restrict__ idx_ws, float* __restrict__ qout,
    float* __restrict__ loss_acc, const float* __restrict__ flat_c,
    const float* __restrict__ ema_w, const float* __restrict__ rcp,
    float* __restrict__ out_emb, float* __restrict__ out_emaw)
{
    __shared__ float shmem[64 * 133];
    __shared__ int idxs[64];
    __shared__ float lsum[8];
    const int tid = threadIdx.x;
    const int bid = blockIdx.x;
    if (bid < 1024) {
        const int n0 = bid * 64;
        const int b = n0 >> 10;
        const int hw0 = n0 & (HW - 1);
        if (tid < 64) idxs[tid] = idx_ws[n0 + tid];
        __syncthreads();
        #pragma unroll
        for (int it = 0; it < 4; ++it) {
            int lin = it * 512 + tid;
            int r = lin >> 5, c4 = lin & 31;
            float4 v = *(const float4*)(embed + (size_t)idxs[r] * DIM + c4 * 4);
            *(float4*)&shmem[r * 133 + c4 * 4] = v;
        }
        __syncthreads();
        const float* zb = ze + (size_t)b * (DIM * HW) + hw0;
        float* qb = qout + (size_t)b * (DIM * HW) + hw0;
        const int hwl = tid & 63;
        float lacc = 0.f;
        #pragma unroll 4
        for (int dd = 0; dd < 16; ++dd) {
            int d = dd * 8 + (tid >> 6);
            float val = shmem[hwl * 133 + d];
            size_t off = (size_t)d * HW + hwl;
            float z = zb[off];
            qb[off] = val;
            float diff = val - z;
            lacc = fmaf(diff, diff, lacc);
        }
        #pragma unroll
        for (int off = 32; off >= 1; off >>= 1) lacc += __shfl_xor(lacc, off, 64);
        if ((tid & 63) == 0) lsum[tid >> 6] = lacc;
        __syncthreads();
        if (tid == 0) {
            float s = ((lsum[0] + lsum[1]) + (lsum[2] + lsum[3]))
                    + ((lsum[4] + lsum[5]) + (lsum[6] + lsum[7]));
            atomicAdd(loss_acc, s);
        }
    } else {
        float (*part)[128] = (float(*)[128])shmem;
        const int k = bid - 1024;
        const int lane = tid & 63;
        const int w = tid >> 6;
        float lo = 0.f, hi = 0.f;
        const int nbeg = w * (NTOT / 8);
        const int nend = nbeg + (NTOT / 8);
        for (int base = nbeg; base < nend; base += 64) {
            int my = idx_ws[base + lane];
            unsigned long long m = __ballot(my == k);
            while (m) {
                int bit = __ffsll((long long)m) - 1;
                m &= m - 1;
                const float* row = flat_c + (size_t)(base + bit) * DIM;
                lo += row[lane];
                hi += row[lane + 64];
            }
        }
        part[w][lane] = lo;
        part[w][lane + 64] = hi;
        __syncthreads();
        if (w == 0) {
            float a = part[0][lane], bsum = part[0][lane + 64];
            #pragma unroll
            for (int u = 1; u < 8; ++u) {
                a += part[u][lane];
                bsum += part[u][lane + 64];
            }
            const float r = rcp[k];
            int elo = k * DIM + lane, ehi = elo + 64;
            float nwa = DECAY * ema_w[elo] + OMD * a;
            float nwb = DECAY * ema_w[ehi] + OMD * bsum;
            out_emaw[elo] = nwa;
            out_emaw[ehi] = nwb;
            out_emb[elo] = nwa * r;
            out_emb[ehi] = nwb * r;
        }
    }
}

// ---- fallback-only kernels (verified exact path) ----
__global__ __launch_bounds__(256, 2) void kargmin(
    const float* __restrict__ ze, const float* __restrict__ embed,
    const float* __restrict__ norm2, const float* nxg,
    int* idx_ws, float* __restrict__ idx_out,
    unsigned int* __restrict__ hist)
{
    __shared__ float xs[128 * 36];
    __shared__ float es[128 * 36];
    __shared__ float nxs[128];
    const int tid = threadIdx.x;
    const int tx = tid & 15, ty = tid >> 4;
    const int n0 = blockIdx.x * 128;
    const float* zbase = ze + (size_t)(n0 >> 10) * (DIM * HW) + (n0 & (HW - 1));
    if (tid < 128) nxs[tid] = nxg[n0 + tid];
    float minv[8];
    int   mini[8];
    #pragma unroll
    for (int i = 0; i < 8; ++i) { minv[i] = 3.4e38f; mini[i] = 0; }
    for (int kt = 0; kt < 8; ++kt) {
        float acc[8][8];
        #pragma unroll
        for (int i = 0; i < 8; ++i)
            #pragma unroll
            for (int j = 0; j < 8; ++j) acc[i][j] = 0.f;
        for (int dc = 0; dc < 4; ++dc) {
            __syncthreads();
            #pragma unroll
            for (int it = 0; it < 4; ++it) {
                int lin = it * 256 + tid;
                int r  = lin & 127;
                int gu = lin >> 7;
                const float* gp = zbase + (size_t)(dc * 32 + gu * 4) * HW + r;
                float4 v;
                v.x = gp[0]; v.y = gp[HW]; v.z = gp[2 * HW]; v.w = gp[3 * HW];
                *(float4*)&xs[r * 36 + gu * 4] = v;
            }
            #pragma unroll
            for (int it = 0; it < 4; ++it) {
                int lin = it * 256 + tid;
                int k  = lin >> 3;
                int gu = lin & 7;
                float4 v = *(const float4*)(embed + (size_t)(kt * 128 + k) * DIM + dc * 32 + gu * 4);
                *(float4*)&es[k * 36 + gu * 4] = v;
            }
            __syncthreads();
            #pragma unroll
            for (int g = 0; g < 8; ++g) {
                float4 xf[8];
                #pragma unroll
                for (int i = 0; i < 8; ++i)
                    xf[i] = *(const float4*)&xs[(ty + i * 16) * 36 + g * 4];
                #pragma unroll
                for (int j = 0; j < 8; ++j) {
                    float4 ef = *(const float4*)&es[(tx + j * 16) * 36 + g * 4];
                    #pragma unroll
                    for (int i = 0; i < 8; ++i) {
                        acc[i][j] = fmaf(xf[i].x, ef.x, acc[i][j]);
                        acc[i][j] = fmaf(xf[i].y, ef.y, acc[i][j]);
                        acc[i][j] = fmaf(xf[i].z, ef.z, acc[i][j]);
                        acc[i][j] = fmaf(xf[i].w, ef.w, acc[i][j]);
                    }
                }
            }
        }
        #pragma unroll
        for (int j = 0; j < 8; ++j) {
            int kg = kt * 128 + tx + j * 16;
            float nrm = norm2[kg];
            #pragma unroll
            for (int i = 0; i < 8; ++i) {
                float q = __fadd_rn(nxs[ty + i * 16], nrm);
                float t = __fmul_rn(2.f, acc[i][j]);
                float s = __fsub_rn(q, t);
                if (s < minv[i]) { minv[i] = s; mini[i] = kg; }
            }
        }
    }
    #pragma unroll
    for (int i = 0; i < 8; ++i) {
        float v = minv[i]; int ix = mini[i];
        #pragma unroll
        for (int off = 8; off >= 1; off >>= 1) {
            float v2 = __shfl_xor(v, off, 16);
            int   i2 = __shfl_xor(ix, off, 16);
            if (v2 < v || (v2 == v && i2 < ix)) { v = v2; ix = i2; }
        }
        if (tx == 0) {
            int n = n0 + ty + i * 16;
            idx_ws[n] = ix;
            idx_out[n] = (float)ix;
            atomicAdd(&hist[ix], 1u);
        }
    }
}

__global__ __launch_bounds__(256) void kquant(
    const float* __restrict__ ze, const float* __restrict__ embed,
    const int* __restrict__ idx_ws, float* __restrict__ qout,
    float* __restrict__ dw_atomic, float* __restrict__ loss_acc)
{
    __shared__ float q[128 * 133];
    __shared__ int idxs[128];
    __shared__ float lsum[4];
    const int tid = threadIdx.x;
    const int n0 = blockIdx.x * 128;
    const int b = n0 >> 10;
    const int hw0 = n0 & (HW - 1);
    if (tid < 128) idxs[tid] = idx_ws[n0 + tid];
    __syncthreads();
    #pragma unroll
    for (int it = 0; it < 16; ++it) {
        int r = it * 8 + (tid >> 5);
        int c = tid & 31;
        float4 v = *(const float4*)(embed + (size_t)idxs[r] * DIM + c * 4);
        *(float4*)&q[r * 133 + c * 4] = v;
    }
    __syncthreads();
    const float* zb = ze + (size_t)b * (DIM * HW) + hw0;
    float* qb = qout + (size_t)b * (DIM * HW) + hw0;
    float lacc = 0.f;
    for (int dd = 0; dd < 64; ++dd) {
        int d = dd * 2 + (tid >> 7);
        int hw = tid & 127;
        float val = q[hw * 133 + d];
        size_t off = (size_t)d * HW + hw;
        float z = zb[off];
        qb[off] = val;
        float diff = val - z;
        lacc = fmaf(diff, diff, lacc);
        if (dw_atomic) atomicAdd(&dw_atomic[idxs[hw] * DIM + d], z);
    }
    #pragma unroll
    for (int off = 32; off >= 1; off >>= 1) lacc += __shfl_xor(lacc, off, 64);
    if ((tid & 63) == 0) lsum[tid >> 6] = lacc;
    __syncthreads();
    if (tid == 0) atomicAdd(loss_acc, lsum[0] + lsum[1] + lsum[2] + lsum[3]);
}

__global__ __launch_bounds__(256) void kfin1(
    const unsigned int* __restrict__ hist, const float* __restrict__ ema_cs,
    float* __restrict__ out_ecs, float* __restrict__ rcp,
    float* __restrict__ loss_out, const float* __restrict__ loss_acc)
{
    const int tid = threadIdx.x;
    __shared__ float wsum[4];
    float local = 0.f;
    float necs[4];
    #pragma unroll
    for (int u = 0; u < 4; ++u) {
        int k = u * 256 + tid;
        necs[u] = DECAY * ema_cs[k] + OMD * (float)hist[k];
        out_ecs[k] = necs[u];
        local += necs[u];
    }
    #pragma unroll
    for (int off = 32; off >= 1; off >>= 1) local += __shfl_xor(local, off, 64);
    if ((tid & 63) == 0) wsum[tid >> 6] = local;
    __syncthreads();
    float ntot = wsum[0] + wsum[1] + wsum[2] + wsum[3];
    #pragma unroll
    for (int u = 0; u < 4; ++u) {
        int k = u * 256 + tid;
        float cs = (necs[u] + EPS) / (ntot + (float)K_CODES * EPS) * ntot;
        rcp[k] = 1.f / cs;
    }
    if (tid == 0) loss_out[0] = loss_acc[0] * (CCOEF / (float)((size_t)NTOT * DIM));
}

__global__ __launch_bounds__(256) void kfin2(
    const float* __restrict__ ema_w, const float* __restrict__ dw,
    const float* __restrict__ rcp, float* __restrict__ out_emb,
    float* __restrict__ out_emaw)
{
    int e = blockIdx.x * 256 + threadIdx.x;
    int k = e >> 7;
    float nw = DECAY * ema_w[e] + OMD * dw[e];
    out_emaw[e] = nw;
    out_emb[e] = nw * rcp[k];
}

extern "C" void kernel_launch(void* const* d_in, const int* in_sizes, int n_in,
                              void* d_out, int out_size, void* d_ws, size_t ws_size,
                              hipStream_t stream) {
    const float* ze     = (const float*)d_in[0];
    const float* embed  = (const float*)d_in[1];
    const float* ema_cs = (const float*)d_in[2];
    const float* ema_w  = (const float*)d_in[3];
    float* out = (float*)d_out;

    float* ws = (float*)d_ws;
    float*          ws_norm2 = ws + W_NORM2;
    float*          ws_rcp   = ws + W_RCP;
    unsigned*       ws_hist  = (unsigned*)(ws + W_HIST);
    float*          ws_loss  = ws + W_LOSS;
    unsigned*       ws_flcnt = (unsigned*)(ws + W_FLCNT);
    unsigned*       ws_cnt   = (unsigned*)(ws + W_CNT2);
    unsigned*       ws_fl    = (unsigned*)(ws + W_FL);
    float*          ws_m1    = ws + W_M1F;
    unsigned*       ws_cand  = (unsigned*)(ws + W_CAND);
    float*          ws_dw    = ws + W_CAND;                // fallback alias
    unsigned short* ws_eh    = (unsigned short*)(ws + W_EH);
    unsigned short* ws_el    = (unsigned short*)(ws + W_EL);
    float*          ws_nx    = ws + W_NXIDX;               // aliased with idx
    int*            ws_idx   = (int*)(ws + W_NXIDX);
    float*          ws_flat  = ws + W_FLAT;
    const size_t need = (size_t)W_NEED * sizeof(float);
    const bool big_ws = ws_size >= need;

    if (big_ws) {
        hipLaunchKernelGGL(kpre, dim3(640), dim3(256), 0, stream,
                           ze, ws_nx, ws_flat, embed, ws_norm2, ws_eh, ws_el,
                           (float*)ws_hist, 25604);
        hipLaunchKernelGGL(kapprox, dim3(1024), dim3(256), 0, stream,
                           ws_flat, ws_eh, ws_el, ws_norm2,
                           ws_idx, out + OFF_IDX, ws_hist, ws_flcnt, ws_fl, ws_m1);
        hipLaunchKernelGGL(kapprox2, dim3(512), dim3(256), 0, stream,
                           ws_flat, ws_eh, ws_el, ws_norm2,
                           ws_m1, ws_flcnt, ws_fl, ws_cnt, ws_cand);
        hipLaunchKernelGGL(krescore, dim3(64), dim3(256), 0, stream,
                           ws_flat, embed, ws_norm2, ws_nx, ws_flcnt, ws_fl,
                           ws_cnt, ws_cand, ws_idx, out + OFF_IDX, ws_hist);
        hipLaunchKernelGGL(kfin_r, dim3(1), dim3(256), 0, stream,
                           ws_hist, ema_cs, out + OFF_ECS, ws_rcp);
        hipLaunchKernelGGL(ktail, dim3(2048), dim3(512), 0, stream,
                           ze, embed, ws_idx, out + OFF_Q, ws_loss,
                           ws_flat, ema_w, ws_rcp, out + OFF_EMB, out + OFF_EMAW);
        hipLaunchKernelGGL(kloss, dim3(1), dim3(64), 0, stream,
                           out + OFF_LOSS, ws_loss);
    } else {
        hipLaunchKernelGGL(kpre, dim3(640), dim3(256), 0, stream,
                           ze, ws_nx, (float*)nullptr, embed, ws_norm2,
                           (unsigned short*)nullptr, (unsigned short*)nullptr,
                           (float*)ws_hist, 1028);
        hipLaunchKernelGGL(kzero, dim3(512), dim3(256), 0, stream, ws_dw, 131072);
        hipLaunchKernelGGL(kargmin, dim3(512), dim3(256), 0, stream,
                           ze, embed, ws_norm2, ws_nx, ws_idx, out + OFF_IDX, ws_hist);
        hipLaunchKernelGGL(kquant, dim3(512), dim3(256), 0, stream,
                           ze, embed, ws_idx, out + OFF_Q, ws_dw, ws_loss);
        hipLaunchKernelGGL(kfin1, dim3(1), dim3(256), 0, stream,
                           ws_hist, ema_cs, out + OFF_ECS, ws_rcp, out + OFF_LOSS, ws_loss);
        hipLaunchKernelGGL(kfin2, dim3(512), dim3(256), 0, stream,
                           ema_w, ws_dw, ws_rcp, out + OFF_EMB, out + OFF_EMAW);
    }
}